// Round 10
// baseline (298.690 us; speedup 1.0000x reference)
//
#include <hip/hip_runtime.h>
#include <hip/hip_bf16.h>

typedef float f32x4 __attribute__((ext_vector_type(4)));
typedef short bf16x8 __attribute__((ext_vector_type(8)));
typedef unsigned short us8 __attribute__((ext_vector_type(8)));

__device__ __forceinline__ unsigned short f2bf(float f) {
  union { float f; unsigned u; } v; v.f = f;
  return (unsigned short)((v.u + 0x8000u) >> 16);   // round-half-up bf16
}
__device__ __forceinline__ float bf2f(unsigned short u) {
  union { unsigned u; float f; } v; v.u = ((unsigned)u) << 16;
  return v.f;
}

// ---------------------------------------------------------------------------
// Kernel 1: VmatT[b][n][p] (bf16), n = c*16+u*4+v (256), p = pi*64+pj (4096)
// ---------------------------------------------------------------------------
__global__ __launch_bounds__(256) void prep_vmat(const float* __restrict__ x,
                                                 unsigned short* __restrict__ vmatT) {
  int t = blockIdx.x * 256 + threadIdx.x;
  int pc = t & 511;
  int n  = (t >> 9) & 255;
  int b  = t >> 17;
  int c = n >> 4, u = (n >> 2) & 3, v = n & 3;
  int pi = pc >> 3;
  int pj0 = (pc & 7) << 3;
  int row = 2 * pi + u - 1;
  row = row < 0 ? 0 : (row > 127 ? 127 : row);
  const float* xr = x + ((size_t)(b * 16 + c) * 128 + row) * 128;
  us8 o;
#pragma unroll
  for (int e = 0; e < 8; ++e) {
    int col = 2 * (pj0 + e) + v - 1;
    col = col < 0 ? 0 : (col > 127 ? 127 : col);
    o[e] = f2bf(xr[col]);
  }
  *reinterpret_cast<us8*>(vmatT + (size_t)t * 8) = o;
}

// ---------------------------------------------------------------------------
// Kernel 2: partial[ks][b][q][n] (bf16) = sum_{p in half ks} scores*VmatT
// K-SPLIT 2: 1024 blocks (batch 8 x qb 64 x ks 2), each K=2048, BK=32,
// 64 tiles. 4 waves, M-split (wave = 16 q-rows x all 256 n).
// LDS = B ring-2 at 2 x 16 KB = 32 KB/block -> 4 blocks/CU, 16 waves/CU:
// 4-way independent-block overlap hides the per-iteration vmcnt+barrier
// convoy (R3/R7 both show ~2000 cyc/iter overhead at 2 blocks/CU).
//  - A: per-lane direct fragment (row l15, k=l16*8), 2 tiles ahead (rE/rO,
//    2 f32x4 each); CONV extracts to fe/fo BEFORE the reload.
//  - B: global_load_lds 16B x4/thread, 1 tile ahead, ring-2; 64-B rows:
//    source slot pre-swizzled gs = sl ^ ((row>>1)&3); read slot same XOR.
//  - per iter: CONV; STAGE_B(kt+1)[4 vm]; LOAD_A(kt+2)[2 vm]; 16 MFMA;
//    vmcnt(2) leaves A(kt+2) in flight across the single barrier.
//  - phase rotation (inner&63) spreads DRAM columns across blocks.
//  - uniform 64 iters; tail prefetches wrap (&63), kept alive by asm.
// ---------------------------------------------------------------------------
__global__ __launch_bounds__(256, 4) void gemm_scores_vmat(
    const float* __restrict__ scores,
    const unsigned short* __restrict__ vmatT,
    unsigned short* __restrict__ AmatP) {
  __shared__ unsigned short ldsB[2][8192];    // 256 rows x 32 bf16, x2

  int bid = blockIdx.x;                        // 1024 blocks
  int batch = bid & 7;                         // = XCD id
  int inner = bid >> 3;                        // 0..127
  int qb = (inner & 63) << 6;
  int ksp = inner >> 6;                        // K-split half
  const int phase = inner & 63;

  const int t = threadIdx.x;
  const int lane = t & 63;
  const int wq = t >> 6;                       // wave id = M-quadrant
  const int l15 = lane & 15, l16 = lane >> 4;

  const size_t kbase = (size_t)ksp * 2048;
  // A: per-lane fragment base (row = qb + wq*16 + l15, k-offset l16*8)
  const float* aLane = scores +
      ((size_t)(batch * 4096 + qb + wq * 16 + l15)) * 4096 + kbase + l16 * 8;
  const unsigned short* Vb = vmatT + (size_t)batch * 256 * 4096 + kbase;

  // B staging: 4 chunks/thread; LDS dest linear, global source slot swizzled
  const unsigned short* bSrc[4];
#pragma unroll
  for (int i = 0; i < 4; ++i) {
    int c = t + i * 256;                       // 0..1023
    int gs = (c & 3) ^ ((c >> 3) & 3);         // sl ^ ((row>>1)&3)
    bSrc[i] = Vb + (size_t)(c >> 2) * 4096 + gs * 8;
  }
  // read-side swizzled slot (elems): sl = l16 ^ ((l15>>1)&3)
  const int rsw = (l16 ^ ((l15 >> 1) & 3)) << 3;

  f32x4 acc[16];
#pragma unroll
  for (int ni = 0; ni < 16; ++ni) acc[ni] = (f32x4){0.f, 0.f, 0.f, 0.f};

  f32x4 rE[2], rO[2];       // two named A reg sets (8 floats each)
  bf16x8 fe, fo;

#define SB __builtin_amdgcn_sched_barrier(0)
#define STAGE_B(kt, bufi)                                                     \
  {                                                                           \
    int kp_ = ((kt) + phase) & 63;                                            \
    _Pragma("unroll") for (int i = 0; i < 4; ++i)                             \
        __builtin_amdgcn_global_load_lds(                                     \
            (const __attribute__((address_space(1))) void*)(bSrc[i] + (size_t)kp_ * 32), \
            (__attribute__((address_space(3))) void*)&ldsB[bufi][(t + i * 256) * 8], \
            16, 0, 0);                                                        \
  }
#define LOAD_A(kt, rr)                                                        \
  {                                                                           \
    int kp_ = ((kt) + phase) & 63;                                            \
    const float* ap_ = aLane + (size_t)kp_ * 32;                              \
    rr[0] = *(const f32x4*)(ap_);                                             \
    rr[1] = *(const f32x4*)(ap_ + 4);                                         \
  }
#define CONV(rr, fa)                                                          \
  {                                                                           \
    _Pragma("unroll") for (int e = 0; e < 4; ++e) {                           \
      fa[e] = (short)f2bf(rr[0][e]); fa[e + 4] = (short)f2bf(rr[1][e]);       \
    }                                                                         \
  }
#define MFMAS(fa, bufi)                                                       \
  {                                                                           \
    _Pragma("unroll") for (int ni = 0; ni < 16; ++ni) {                       \
      bf16x8 bv = *(const bf16x8*)(&ldsB[bufi][0] +                           \
                                   (ni * 16 + l15) * 32 + rsw);               \
      acc[ni] = __builtin_amdgcn_mfma_f32_16x16x32_bf16(fa, bv, acc[ni],      \
                                                        0, 0, 0);             \
    }                                                                         \
  }

  // ---- prologue: A(0)->rE, B(0)->buf0, A(1)->rO; A(1) rides the barrier
  LOAD_A(0, rE);
  SB;
  STAGE_B(0, 0);
  SB;
  LOAD_A(1, rO);
  SB;
  asm volatile("s_waitcnt vmcnt(2)" ::: "memory");  // A0,B0 landed
  SB;
  __builtin_amdgcn_s_barrier();
  SB;

  // ---- main loop: 64 uniform iters, unrolled x2 (static reg-set roles)
  for (int kt = 0; kt < 64; kt += 2) {
    // EVEN: consume rE=A(kt), buf0=B(kt)
    CONV(rE, fe);               // extract BEFORE reload
    SB;
    STAGE_B(kt + 1, 1);
    SB;
    LOAD_A(kt + 2, rE);
    SB;
    MFMAS(fe, 0);
    asm volatile("s_waitcnt vmcnt(2)" ::: "memory");  // A(kt+1),B(kt+1) landed
    SB;
    __builtin_amdgcn_s_barrier();
    SB;
    // ODD: consume rO=A(kt+1), buf1=B(kt+1)
    CONV(rO, fo);
    SB;
    STAGE_B(kt + 2, 0);
    SB;
    LOAD_A(kt + 3, rO);
    SB;
    MFMAS(fo, 1);
    asm volatile("s_waitcnt vmcnt(2)" ::: "memory");
    SB;
    __builtin_amdgcn_s_barrier();
    SB;
  }

  // keep tail prefetches live so the vmcnt FIFO accounting stays exact
  asm volatile("" ::"v"(rE[0][0]), "v"(rE[1][0]), "v"(rO[0][0]), "v"(rO[1][0]));

#undef SB
#undef STAGE_B
#undef LOAD_A
#undef CONV
#undef MFMAS

  // C-write to partial ksp: rows qb+wq*16+l16*4+j, col ni*16+l15
  unsigned short* Ao = AmatP + (size_t)ksp * 8 * 4096 * 256 +
                       ((size_t)(batch * 4096 + qb + wq * 16)) * 256;
#pragma unroll
  for (int ni = 0; ni < 16; ++ni)
#pragma unroll
    for (int j = 0; j < 4; ++j)
      Ao[(size_t)(l16 * 4 + j) * 256 + ni * 16 + l15] = f2bf(acc[ni][j]);
}

// ---------------------------------------------------------------------------
// Kernel 3: out = x + alpha/4 * gathered conv_transpose contributions,
// summing the two K-split partials.
// ---------------------------------------------------------------------------
__global__ __launch_bounds__(256) void epilogue_kernel(
    const float* __restrict__ x, const unsigned short* __restrict__ AmatP,
    const float* __restrict__ alpha, float* __restrict__ out) {
  int b = blockIdx.x >> 7;
  int h = blockIdx.x & 127;
  int t = threadIdx.x;
  int w = t & 127;
  int cg = t >> 7;

  int ihi = (h + 1) >> 1, u_hi = (h + 1) & 1;
  int jhi = (w + 1) >> 1, v_hi = (w + 1) & 1;
  bool vi_hi = (ihi <= 63), vi_lo = (ihi >= 1);
  bool vj_hi = (jhi <= 63), vj_lo = (jhi >= 1);

  float al = alpha[0] * 0.25f;
  const unsigned short* A0 = AmatP + (size_t)b * 4096 * 256;
  const unsigned short* A1 = A0 + (size_t)8 * 4096 * 256;

#pragma unroll
  for (int cc = 0; cc < 8; ++cc) {
    int c = cg * 8 + cc;
    float s = 0.f;
    if (vi_hi) {
      size_t base = (size_t)(ihi * 64) * 256 + c * 16 + u_hi * 4;
      if (vj_hi) {
        size_t i0 = base + jhi * 256 + v_hi;
        s += bf2f(A0[i0]) + bf2f(A1[i0]);
      }
      if (vj_lo) {
        size_t i0 = base + (jhi - 1) * 256 + v_hi + 2;
        s += bf2f(A0[i0]) + bf2f(A1[i0]);
      }
    }
    if (vi_lo) {
      size_t base = (size_t)((ihi - 1) * 64) * 256 + c * 16 + (u_hi + 2) * 4;
      if (vj_hi) {
        size_t i0 = base + jhi * 256 + v_hi;
        s += bf2f(A0[i0]) + bf2f(A1[i0]);
      }
      if (vj_lo) {
        size_t i0 = base + (jhi - 1) * 256 + v_hi + 2;
        s += bf2f(A0[i0]) + bf2f(A1[i0]);
      }
    }
    size_t xi = (((size_t)b * 16 + c) * 128 + h) * 128 + w;
    out[xi] = x[xi] + al * s;
  }
}

extern "C" void kernel_launch(void* const* d_in, const int* in_sizes, int n_in,
                              void* d_out, int out_size, void* d_ws, size_t ws_size,
                              hipStream_t stream) {
  const float* x      = (const float*)d_in[0];
  const float* scores = (const float*)d_in[1];
  const float* alpha  = (const float*)d_in[2];
  float* out = (float*)d_out;

  // ws: VmatT bf16 16 MB | AmatP bf16 2 x 16 MB
  unsigned short* vmatT = (unsigned short*)d_ws;
  unsigned short* AmatP = (unsigned short*)((char*)d_ws + (size_t)16 * 1024 * 1024);

  prep_vmat<<<4096, 256, 0, stream>>>(x, vmatT);
  gemm_scores_vmat<<<1024, 256, 0, stream>>>(scores, vmatT, AmatP);
  epilogue_kernel<<<1024, 256, 0, stream>>>(x, AmatP, alpha, out);
}

// Round 11
// 210.749 us; speedup vs baseline: 1.4173x; 1.4173x over previous
//
#include <hip/hip_runtime.h>
#include <hip/hip_bf16.h>

typedef float f32x4 __attribute__((ext_vector_type(4)));
typedef short bf16x8 __attribute__((ext_vector_type(8)));
typedef unsigned short us8 __attribute__((ext_vector_type(8)));

__device__ __forceinline__ unsigned short f2bf(float f) {
  union { float f; unsigned u; } v; v.f = f;
  return (unsigned short)((v.u + 0x8000u) >> 16);   // round-half-up bf16
}
__device__ __forceinline__ float bf2f(unsigned short u) {
  union { unsigned u; float f; } v; v.u = ((unsigned)u) << 16;
  return v.f;
}

// ---------------------------------------------------------------------------
// Kernel 1: VmatT[b][n][p] (bf16), n = c*16+u*4+v (256), p = pi*64+pj (4096)
// ---------------------------------------------------------------------------
__global__ __launch_bounds__(256) void prep_vmat(const float* __restrict__ x,
                                                 unsigned short* __restrict__ vmatT) {
  int t = blockIdx.x * 256 + threadIdx.x;
  int pc = t & 511;
  int n  = (t >> 9) & 255;
  int b  = t >> 17;
  int c = n >> 4, u = (n >> 2) & 3, v = n & 3;
  int pi = pc >> 3;
  int pj0 = (pc & 7) << 3;
  int row = 2 * pi + u - 1;
  row = row < 0 ? 0 : (row > 127 ? 127 : row);
  const float* xr = x + ((size_t)(b * 16 + c) * 128 + row) * 128;
  us8 o;
#pragma unroll
  for (int e = 0; e < 8; ++e) {
    int col = 2 * (pj0 + e) + v - 1;
    col = col < 0 ? 0 : (col > 127 ? 127 : col);
    o[e] = f2bf(xr[col]);
  }
  *reinterpret_cast<us8*>(vmatT + (size_t)t * 8) = o;
}

// ---------------------------------------------------------------------------
// Kernel 2: A[b][q][n] (bf16) = sum_p scores[b][q][p] * VmatT[b][n][p]
// M=4096, N=256, K=4096. BQ=64, BK=128 -> 32 K-tiles. 4 waves, M-split
// (wave = 16 q-rows x all 256 n). LDS = B ring-2 at 2 x 64 KB = 128 KB
// static -> 1 block/CU, 64 barrier-iters/CU (HALF of R7's 128; R10 showed
// per-barrier-iteration overhead ~2000 cyc dominates, so minimize iters).
//  - A (scores, HBM): per-lane direct MFMA fragments (row l15, k=l16*8),
//    4 frags/tile = 8 dwordx4, reg-staged 2 tiles ahead (rE/rO); CONV
//    extracts to fa[4] BEFORE the set is overwritten.
//  - B (VmatT, L2-resident): global_load_lds 16B x16/thread, 1 tile ahead,
//    ring-2. 256-B rows -> 16-slot XOR swizzle slot' = slot ^ (row&15):
//    global source pre-swizzled, read side same XOR (involution).
//  - per iter: CONV; STAGE_B(kt+1)[16 vm]; LOAD_A(kt+2)[8 vm]; 64 MFMA;
//    vmcnt(8) leaves A(kt+2) in flight across the single barrier.
//  - K-phase rotation (qbi&31) spreads DRAM/L2 access across blocks.
//  - uniform 32 iters; tail prefetches wrap (&31), kept alive by asm so
//    the vmcnt FIFO accounting stays exact. K-coverage: 32*128 = 4096 ✓.
// ---------------------------------------------------------------------------
__global__ __launch_bounds__(256, 1) void gemm_scores_vmat(
    const float* __restrict__ scores,
    const unsigned short* __restrict__ vmatT,
    unsigned short* __restrict__ Amat) {
  __shared__ unsigned short ldsB[2][32768];   // 256 rows x 128 bf16, x2 (128 KB)

  int bid = blockIdx.x;
  int nb = ((bid & 7) << 6) | (bid >> 3);     // batch = XCD id
  int batch = nb >> 6;
  int qb = (nb & 63) << 6;
  const int phase = (bid >> 3) & 31;

  const int t = threadIdx.x;
  const int lane = t & 63;
  const int wq = t >> 6;                      // wave id = M-quadrant
  const int l15 = lane & 15, l16 = lane >> 4;

  // A: per-lane fragment base (row = qb + wq*16 + l15, k-offset l16*8)
  const float* aLane =
      scores + ((size_t)(batch * 4096 + qb + wq * 16 + l15)) * 4096 + l16 * 8;
  const unsigned short* Vb = vmatT + (size_t)batch * 256 * 4096;

  // B staging: 16 chunks/thread; LDS dest linear, global source slot
  // pre-swizzled: chunk c -> row c>>4, slot (c&15) ^ ((c>>4)&15)
  const unsigned short* bSrc[16];
#pragma unroll
  for (int i = 0; i < 16; ++i) {
    int c = t + i * 256;                      // 0..4095
    int gs = (c & 15) ^ ((c >> 4) & 15);
    bSrc[i] = Vb + (size_t)(c >> 4) * 4096 + gs * 8;
  }

  f32x4 acc[16];
#pragma unroll
  for (int ni = 0; ni < 16; ++ni) acc[ni] = (f32x4){0.f, 0.f, 0.f, 0.f};

  f32x4 rE[8], rO[8];     // two named A reg sets (tile = 4 frags = 8 f32x4)
  bf16x8 fe[4], fo[4];

#define SB __builtin_amdgcn_sched_barrier(0)
#define STAGE_B(kt, bufi)                                                     \
  {                                                                           \
    int kp_ = ((kt) + phase) & 31;                                            \
    _Pragma("unroll") for (int i = 0; i < 16; ++i)                            \
        __builtin_amdgcn_global_load_lds(                                     \
            (const __attribute__((address_space(1))) void*)(bSrc[i] + (size_t)kp_ * 128), \
            (__attribute__((address_space(3))) void*)&ldsB[bufi][(t + i * 256) * 8], \
            16, 0, 0);                                                        \
  }
#define LOAD_A(kt, rr)                                                        \
  {                                                                           \
    int kp_ = ((kt) + phase) & 31;                                            \
    const float* ap_ = aLane + (size_t)kp_ * 128;                             \
    rr[0] = *(const f32x4*)(ap_);                                             \
    rr[1] = *(const f32x4*)(ap_ + 4);                                         \
    rr[2] = *(const f32x4*)(ap_ + 32);                                        \
    rr[3] = *(const f32x4*)(ap_ + 36);                                        \
    rr[4] = *(const f32x4*)(ap_ + 64);                                        \
    rr[5] = *(const f32x4*)(ap_ + 68);                                        \
    rr[6] = *(const f32x4*)(ap_ + 96);                                        \
    rr[7] = *(const f32x4*)(ap_ + 100);                                       \
  }
#define CONV(rr, ff)                                                          \
  {                                                                           \
    _Pragma("unroll") for (int f = 0; f < 4; ++f)                             \
        _Pragma("unroll") for (int e = 0; e < 4; ++e) {                       \
      ff[f][e]     = (short)f2bf(rr[2 * f][e]);                               \
      ff[f][e + 4] = (short)f2bf(rr[2 * f + 1][e]);                           \
    }                                                                         \
  }
#define MFMAS(ff, bufi)                                                       \
  {                                                                           \
    _Pragma("unroll") for (int ks = 0; ks < 4; ++ks)                          \
        _Pragma("unroll") for (int ni = 0; ni < 16; ++ni) {                   \
      int slot = (ks * 4 + l16) ^ l15;                                        \
      bf16x8 bv = *(const bf16x8*)(&ldsB[bufi][0] +                           \
                                   (ni * 16 + l15) * 128 + slot * 8);         \
      acc[ni] = __builtin_amdgcn_mfma_f32_16x16x32_bf16(ff[ks], bv, acc[ni],  \
                                                        0, 0, 0);             \
    }                                                                         \
  }

  // ---- prologue: A(0)->rE [8], B(0)->buf0 [16], A(1)->rO [8]
  LOAD_A(0, rE);
  SB;
  STAGE_B(0, 0);
  SB;
  LOAD_A(1, rO);
  SB;
  asm volatile("s_waitcnt vmcnt(8)" ::: "memory");  // A0,B0 landed; A1 rides
  SB;
  __builtin_amdgcn_s_barrier();
  SB;

  // ---- main loop: 32 uniform iters, unrolled x2 (static reg-set roles)
  for (int kt = 0; kt < 32; kt += 2) {
    // EVEN: consume rE=A(kt), buf0=B(kt)
    CONV(rE, fe);               // extract BEFORE reload
    SB;
    STAGE_B(kt + 1, 1);
    SB;
    LOAD_A(kt + 2, rE);
    SB;
    MFMAS(fe, 0);
    asm volatile("s_waitcnt vmcnt(8)" ::: "memory");  // A(kt+1),B(kt+1) landed
    SB;
    __builtin_amdgcn_s_barrier();
    SB;
    // ODD: consume rO=A(kt+1), buf1=B(kt+1)
    CONV(rO, fo);
    SB;
    STAGE_B(kt + 2, 0);
    SB;
    LOAD_A(kt + 3, rO);
    SB;
    MFMAS(fo, 1);
    asm volatile("s_waitcnt vmcnt(8)" ::: "memory");
    SB;
    __builtin_amdgcn_s_barrier();
    SB;
  }

  // keep tail prefetches live so the vmcnt FIFO accounting stays exact
  asm volatile("" ::"v"(rE[0][0]), "v"(rE[3][0]), "v"(rE[5][0]), "v"(rE[7][0]),
               "v"(rO[0][0]), "v"(rO[3][0]), "v"(rO[5][0]), "v"(rO[7][0]));

#undef SB
#undef STAGE_B
#undef LOAD_A
#undef CONV
#undef MFMAS

  // C-write: wave wq owns q-rows qb+wq*16..+15; row=(l16*4+j), col=l15 per ni
  unsigned short* Ao = Amat + ((size_t)(batch * 4096 + qb + wq * 16)) * 256;
#pragma unroll
  for (int ni = 0; ni < 16; ++ni)
#pragma unroll
    for (int j = 0; j < 4; ++j)
      Ao[(size_t)(l16 * 4 + j) * 256 + ni * 16 + l15] = f2bf(acc[ni][j]);
}

// ---------------------------------------------------------------------------
// Kernel 3: out = x + alpha/4 * gathered conv_transpose contributions
// ---------------------------------------------------------------------------
__global__ __launch_bounds__(256) void epilogue_kernel(
    const float* __restrict__ x, const unsigned short* __restrict__ Amat,
    const float* __restrict__ alpha, float* __restrict__ out) {
  int b = blockIdx.x >> 7;
  int h = blockIdx.x & 127;
  int t = threadIdx.x;
  int w = t & 127;
  int cg = t >> 7;

  int ihi = (h + 1) >> 1, u_hi = (h + 1) & 1;
  int jhi = (w + 1) >> 1, v_hi = (w + 1) & 1;
  bool vi_hi = (ihi <= 63), vi_lo = (ihi >= 1);
  bool vj_hi = (jhi <= 63), vj_lo = (jhi >= 1);

  float al = alpha[0] * 0.25f;
  const unsigned short* Ab = Amat + (size_t)b * 4096 * 256;

#pragma unroll
  for (int cc = 0; cc < 8; ++cc) {
    int c = cg * 8 + cc;
    float s = 0.f;
    if (vi_hi) {
      const unsigned short* Ar = Ab + (size_t)(ihi * 64) * 256 + c * 16 + u_hi * 4;
      if (vj_hi) s += bf2f(Ar[jhi * 256 + v_hi]);
      if (vj_lo) s += bf2f(Ar[(jhi - 1) * 256 + v_hi + 2]);
    }
    if (vi_lo) {
      const unsigned short* Ar = Ab + (size_t)((ihi - 1) * 64) * 256 + c * 16 + (u_hi + 2) * 4;
      if (vj_hi) s += bf2f(Ar[jhi * 256 + v_hi]);
      if (vj_lo) s += bf2f(Ar[(jhi - 1) * 256 + v_hi + 2]);
    }
    size_t xi = (((size_t)b * 16 + c) * 128 + h) * 128 + w;
    out[xi] = x[xi] + al * s;
  }
}

extern "C" void kernel_launch(void* const* d_in, const int* in_sizes, int n_in,
                              void* d_out, int out_size, void* d_ws, size_t ws_size,
                              hipStream_t stream) {
  const float* x      = (const float*)d_in[0];
  const float* scores = (const float*)d_in[1];
  const float* alpha  = (const float*)d_in[2];
  float* out = (float*)d_out;

  unsigned short* vmatT = (unsigned short*)d_ws;
  unsigned short* Amat  = (unsigned short*)((char*)d_ws + (size_t)16 * 1024 * 1024);

  prep_vmat<<<4096, 256, 0, stream>>>(x, vmatT);
  gemm_scores_vmat<<<512, 256, 0, stream>>>(scores, vmatT, Amat);
  epilogue_kernel<<<1024, 256, 0, stream>>>(x, Amat, alpha, out);
}